// Round 14
// baseline (599.248 us; speedup 1.0000x reference)
//
#include <hip/hip_runtime.h>
#include <hip/hip_bf16.h>
#include <stdint.h>

// MutualCrossAttention: B=8, C=64, H=W=64 -> T=4096 tokens. Inputs FP32, output FP32.
// dir A: Q=x1, K=V=x2 ; dir B: Q=x2, K=V=x1 ; out = outA + outB, layout [b][c][t].
// R26: 1024-THREAD BLOCKS (16 waves) — the residency loophole. 13 rounds prove
// the CP never co-schedules a 2nd block/CU for this kernel (R19/R20/R21/R24),
// so TLP was stuck at 8 waves/CU. A block's waves are atomic: 1024 threads
// forces 16 waves/CU = 4/SIMD. Budget: VGPR pool 2048/CU (m69) -> 128/wave;
// R25's 4 prefetch sets (~160) won't fit -> single K + single V set (shallow
// prefetch, still full-phase covered by the parity-reordered schedule below),
// KEEPING R25's parity pbuf (proved +13us: S(j+1) issues before PV(j), so the
// pbuf write->read and the K/V loads each get a full sub-phase of slack).
// Per j-pair (j even):  S(j)->par0 | loadK(j+1) | PV(j-1)<-par1 | loadV(j) |
//                       S(j+1)->par1 | loadK(j+2) | PV(j)<-par0 | loadV(j+1)
// WAR all safe in program order; every load has >=1 sub-phase (~400cy) cover.
// Waves = (dir, pair, ks, qt_sub): each block does 2 qt values; grid 256 = 1/CU.
// LDS: pbuf[16][2par][2rb][16][72] = 144KB + lpx 2KB = 146KB <= 160.
//   kt chunk(tt,mt,ch):  lane(quad,l16) holds K[t=tt*64+mt*16+l16][c=ch*32+quad*8+e]
//   vt chunk(tt,ch2,ct): lane(quad,l16) holds V[c=ct*16+l16][t=tt*64+ch2*32+quad*8+e]
// Q frags are kt chunks at (qt, mt=pair*2+rb, ch) — all hot loads contiguous 1KB.
//   - Barrier-free loop (R23: +4us); S^T composition (A=K,B=Q then A=V,B=P^T);
//     P^T C/D layout -> b64 pbuf write, b128 read, stride-72.
//   - lp scalar per lane; ks-partner = wave^4 via lpx; 4-phase (dir,ks) merge
//     per (qt_sub,pair) group into xbuf overlay; g==0 stores O^T coalesced.
// ws: [0,8MB) kt bf16 frag-packed {x1,x2} PRE-SCALED by sqrt(log2(e)/8);
//     [8MB,16MB) vt bf16 frag-packed {x1,x2} unscaled.

#define TT 4096
#define CC 64
#define NB 8

typedef float f32x4 __attribute__((ext_vector_type(4)));
typedef float f32x4a __attribute__((ext_vector_type(4), may_alias));
typedef short s16x8 __attribute__((ext_vector_type(8)));
typedef unsigned int u32x2a __attribute__((ext_vector_type(2), may_alias));
typedef unsigned int u32x4a __attribute__((ext_vector_type(4), may_alias));
typedef float f32a __attribute__((may_alias));

static __device__ __forceinline__ unsigned fbits(float x) { return __float_as_uint(x); }
static __device__ __forceinline__ ushort bf16of(float v) {
    return (ushort)((fbits(v) + 0x8000u) >> 16);
}
static __device__ __forceinline__ unsigned pack2(float a, float b) {
    return __builtin_amdgcn_perm(fbits(b) + 0x8000u, fbits(a) + 0x8000u, 0x07060302u);
}
static __device__ __forceinline__ s16x8 load_frag(const void* p) {
    u32x4a t = *(const u32x4a*)p;
    return __builtin_bit_cast(s16x8, t);
}

#define SQC1 0.4246609177f  // sqrt(log2(e)/8), applied to kt on both Q and K sides

// grid (TT/64, NB, 2), 256 threads. Reads c-major f32, emits frag-packed bf16.
__global__ void prep_k(const float* __restrict__ x1, const float* __restrict__ x2,
                       ushort* __restrict__ kt, ushort* __restrict__ vt) {
    const int inp = blockIdx.z, b = blockIdx.y, tt = blockIdx.x;
    const float* src = (inp == 0 ? x1 : x2) + (size_t)b * CC * TT;
    const size_t plane = (size_t)TT * CC;
    ushort* kd = kt + (size_t)(inp * NB + b) * plane;
    ushort* vd = vt + (size_t)(inp * NB + b) * plane;
    __shared__ ushort lds[64][72];
    const int tid = threadIdx.x;
    const int c  = tid >> 2;        // 0..63: channel row
    const int tg = tid & 3;         // 16-token group within the 64-token tile
    const float* srow = src + (size_t)c * TT + tt * 64 + tg * 16;
    unsigned hw[8];
#pragma unroll
    for (int i = 0; i < 4; ++i) {
        f32x4a v = *(const f32x4a*)(srow + i * 4);
        hw[2 * i]     = pack2(v[0], v[1]);
        hw[2 * i + 1] = pack2(v[2], v[3]);
#pragma unroll
        for (int k = 0; k < 4; ++k) lds[tg * 16 + i * 4 + k][c] = bf16of(v[k] * SQC1);
    }
    // vt frag-packed (unscaled): thread(c,tg) owns V[c][t_local=tg*16..+16] =
    // chunk(tt, ch2=tg>>1, ct=c>>4), lanes (quad=(tg&1)*2 and +1, l16=c&15).
    {
        ushort* vchunk = vd + (((size_t)tt * 2 + (tg >> 1)) * 4 + (c >> 4)) * 512;
        const int l16v = c & 15;
        const int q0v  = (tg & 1) * 2;
        u32x4a w0 = {hw[0], hw[1], hw[2], hw[3]};
        u32x4a w1 = {hw[4], hw[5], hw[6], hw[7]};
        *(u32x4a*)(vchunk + (size_t)(q0v * 16 + l16v) * 8)       = w0;
        *(u32x4a*)(vchunk + (size_t)((q0v + 1) * 16 + l16v) * 8) = w1;
    }
    __syncthreads();
    // kt frag-packed (scaled, from transposed LDS): tid = mt*64 + quad*16 + l16.
    // chunk(tt, mt, ch): lane holds 8 consecutive c at row t = mt*16 + l16.
    const int mt   = tid >> 6;
    const int quad = (tid >> 4) & 3;
    const int l16  = tid & 15;
    const int t    = mt * 16 + l16;
#pragma unroll
    for (int ch = 0; ch < 2; ++ch) {
        u32x4a w = *(const u32x4a*)&lds[t][ch * 32 + quad * 8];
        *(u32x4a*)(kd + (((size_t)tt * 4 + mt) * 2 + ch) * 512 +
                   (size_t)(quad * 16 + l16) * 8) = w;
    }
}

// grid = 256 blocks (qt2 0..31 x b 0..7), 1024 threads = 16 waves.
// wave: dir = w&1, pair = (w>>1)&1, ks = (w>>2)&1, qt_sub = w>>3.
__global__ __attribute__((amdgpu_flat_work_group_size(1024, 1024)))
void attn_fused_k(const ushort* __restrict__ kt, const ushort* __restrict__ vt,
                  float* __restrict__ out) {
    const int b     = blockIdx.x & 7;
    const int qt2   = blockIdx.x >> 3;
    const int tid   = threadIdx.x;
    const int wave  = tid >> 6;
    const int lane  = tid & 63;
    const int quad  = lane >> 4;
    const int l16   = lane & 15;
    const int dir   = wave & 1;
    const int pair  = (wave >> 1) & 1;
    const int ks    = (wave >> 2) & 1;
    const int qsub  = wave >> 3;
    const int qt    = qt2 * 2 + qsub;
    const int q0    = qt * 64 + pair * 32;

    const size_t plane = (size_t)TT * CC;
    // All hot-loop loads: base + chunk*512 + lane*8 (ushorts) = contiguous 1KB/instr.
    const ushort* Qp = kt + (size_t)((dir == 0 ? 0 : NB) + b) * plane + (size_t)lane * 8;
    const ushort* Kp = kt + (size_t)((dir == 0 ? NB : 0) + b) * plane + (size_t)lane * 8;
    const ushort* Vp = vt + (size_t)((dir == 0 ? NB : 0) + b) * plane + (size_t)lane * 8;

    // Parity pbuf: S(j+1) writes and PV(j) reads touch different regions.
    __shared__ __align__(16) ushort pbuf[16][2][2][16][72];  // 144 KB
    __shared__ float lpx[16][2][16];                         // 2 KB
    f32a* xbuf = (f32a*)&pbuf[0][0][0][0][0];                // 32 KB overlay, post-loop

    // Q b-frags = kt chunks (qt, mt = pair*2 + rb, ch), pre-scaled.
    s16x8 qf[2][2];
#pragma unroll
    for (int rb = 0; rb < 2; ++rb)
#pragma unroll
        for (int ch = 0; ch < 2; ++ch)
            qf[rb][ch] = load_frag(Qp + (((size_t)qt * 4 + pair * 2 + rb) * 2 + ch) * 512);

    f32x4 accO[2][4];  // O^T partial: row=c=quad*4+r (+ct*16), col=q=l16 (+rb*16)
#pragma unroll
    for (int rb = 0; rb < 2; ++rb)
#pragma unroll
        for (int ct = 0; ct < 4; ++ct) accO[rb][ct] = (f32x4){0.f, 0.f, 0.f, 0.f};
    float lp[2] = {0.f, 0.f};

    // SINGLE K set + SINGLE V set (named; arrays spill — R14/R15). 16-wave
    // residency demands <=128 regs/wave: no room for R25's double sets.
    s16x8 kA0, kA1, kA2, kA3, kA4, kA5, kA6, kA7;
    s16x8 vA0, vA1, vA2, vA3, vA4, vA5, vA6, vA7;

    auto loadK = [&](int j) {
        const ushort* p = Kp + (size_t)(ks * 32 + j) * 4096;
        kA0 = load_frag(p);          kA1 = load_frag(p + 512);
        kA2 = load_frag(p + 1024);   kA3 = load_frag(p + 1536);
        kA4 = load_frag(p + 2048);   kA5 = load_frag(p + 2560);
        kA6 = load_frag(p + 3072);   kA7 = load_frag(p + 3584);
    };
    auto loadV = [&](int j) {
        const ushort* p = Vp + (size_t)(ks * 32 + j) * 4096;
        vA0 = load_frag(p);          vA1 = load_frag(p + 512);
        vA2 = load_frag(p + 1024);   vA3 = load_frag(p + 1536);
        vA4 = load_frag(p + 2048);   vA5 = load_frag(p + 2560);
        vA6 = load_frag(p + 3072);   vA7 = load_frag(p + 3584);
    };

    // One mt-slice of S^T into parity region par:
    // D[row=tok=quad*4+r (+mt*16)][col=q=l16] -> b64 P write.
    auto SmT = [&](int mt, int par) {
        s16x8 kc0, kc1;
        if (mt == 0)      { kc0 = kA0; kc1 = kA1; }
        else if (mt == 1) { kc0 = kA2; kc1 = kA3; }
        else if (mt == 2) { kc0 = kA4; kc1 = kA5; }
        else              { kc0 = kA6; kc1 = kA7; }
#pragma unroll
        for (int rb = 0; rb < 2; ++rb) {
            f32x4 s = (f32x4){0.f, 0.f, 0.f, 0.f};
            s = __builtin_amdgcn_mfma_f32_16x16x32_bf16(kc0, qf[rb][0], s, 0, 0, 0);
            s = __builtin_amdgcn_mfma_f32_16x16x32_bf16(kc1, qf[rb][1], s, 0, 0, 0);
            float p0 = __builtin_amdgcn_exp2f(s[0]);
            float p1 = __builtin_amdgcn_exp2f(s[1]);
            float p2 = __builtin_amdgcn_exp2f(s[2]);
            float p3 = __builtin_amdgcn_exp2f(s[3]);
            lp[rb] += (p0 + p1) + (p2 + p3);
            u32x2a w;
            w[0] = pack2(p0, p1);
            w[1] = pack2(p2, p3);
            *(u32x2a*)&pbuf[wave][par][rb][l16][mt * 16 + quad * 4] = w;
        }
    };
    auto Sphase = [&](int par) { SmT(0, par); SmT(1, par); SmT(2, par); SmT(3, par); };

    // PV from parity region par with the (single) V set.
    auto PVphase = [&](int par) {
        s16x8 pf0a = load_frag(&pbuf[wave][par][0][l16][quad * 8]);
        s16x8 pf1a = load_frag(&pbuf[wave][par][1][l16][quad * 8]);
        accO[0][0] = __builtin_amdgcn_mfma_f32_16x16x32_bf16(vA0, pf0a, accO[0][0], 0, 0, 0);
        accO[1][0] = __builtin_amdgcn_mfma_f32_16x16x32_bf16(vA0, pf1a, accO[1][0], 0, 0, 0);
        accO[0][1] = __builtin_amdgcn_mfma_f32_16x16x32_bf16(vA1, pf0a, accO[0][1], 0, 0, 0);
        accO[1][1] = __builtin_amdgcn_mfma_f32_16x16x32_bf16(vA1, pf1a, accO[1][1], 0, 0, 0);
        accO[0][2] = __builtin_amdgcn_mfma_f32_16x16x32_bf16(vA2, pf0a, accO[0][2], 0, 0, 0);
        accO[1][2] = __builtin_amdgcn_mfma_f32_16x16x32_bf16(vA2, pf1a, accO[1][2], 0, 0, 0);
        accO[0][3] = __builtin_amdgcn_mfma_f32_16x16x32_bf16(vA3, pf0a, accO[0][3], 0, 0, 0);
        accO[1][3] = __builtin_amdgcn_mfma_f32_16x16x32_bf16(vA3, pf1a, accO[1][3], 0, 0, 0);
        s16x8 pf0b = load_frag(&pbuf[wave][par][0][l16][32 + quad * 8]);
        s16x8 pf1b = load_frag(&pbuf[wave][par][1][l16][32 + quad * 8]);
        accO[0][0] = __builtin_amdgcn_mfma_f32_16x16x32_bf16(vA4, pf0b, accO[0][0], 0, 0, 0);
        accO[1][0] = __builtin_amdgcn_mfma_f32_16x16x32_bf16(vA4, pf1b, accO[1][0], 0, 0, 0);
        accO[0][1] = __builtin_amdgcn_mfma_f32_16x16x32_bf16(vA5, pf0b, accO[0][1], 0, 0, 0);
        accO[1][1] = __builtin_amdgcn_mfma_f32_16x16x32_bf16(vA5, pf1b, accO[1][1], 0, 0, 0);
        accO[0][2] = __builtin_amdgcn_mfma_f32_16x16x32_bf16(vA6, pf0b, accO[0][2], 0, 0, 0);
        accO[1][2] = __builtin_amdgcn_mfma_f32_16x16x32_bf16(vA6, pf1b, accO[1][2], 0, 0, 0);
        accO[0][3] = __builtin_amdgcn_mfma_f32_16x16x32_bf16(vA7, pf0b, accO[0][3], 0, 0, 0);
        accO[1][3] = __builtin_amdgcn_mfma_f32_16x16x32_bf16(vA7, pf1b, accO[1][3], 0, 0, 0);
    };

    // Barrier-free parity pipeline. Per j-pair (j even):
    //   S(j)->par0 | loadK(j+1) | PV(j-1)<-par1 | loadV(j) |
    //   S(j+1)->par1 | loadK(j+2) | PV(j)<-par0 | loadV(j+1)
    // Every load has >= 1 sub-phase (~400cy) of cover; all WAR hazards resolve
    // in program order (loads issue after their register's last consumer).
    loadK(0);
#pragma unroll 1
    for (int j = 0; j < 32; j += 2) {
        Sphase(0);                       // S(j), uses K(j)
        loadK(j + 1);
        if (j > 0) PVphase(1);           // PV(j-1), uses V(j-1)
        loadV(j);
        Sphase(1);                       // S(j+1), uses K(j+1)
        if (j + 2 < 32) loadK(j + 2);
        PVphase(0);                      // PV(j), uses V(j)
        loadV(j + 1);
    }
    PVphase(1);                          // PV(31), uses V(31)

    // Denominator: quads hold disjoint token subsets for col q=l16.
    float inv[2];
#pragma unroll
    for (int rb = 0; rb < 2; ++rb) {
        float l = lp[rb];
        l += __shfl_xor(l, 16);
        l += __shfl_xor(l, 32);
        lp[rb] = l;
        if (lane < 16) lpx[wave][rb][l16] = l;
    }
    __syncthreads();  // joins ALL 16 waves after their last pbuf use ->
                      // xbuf overlay safe; lpx visible
#pragma unroll
    for (int rb = 0; rb < 2; ++rb)
        inv[rb] = __builtin_amdgcn_rcpf(lp[rb] + lpx[wave ^ 4][rb][l16]);

    // 4-phase merge over g = (ks,dir) within each (qsub,pair) group; g==0 stores.
    const int g = (ks << 1) | dir;
    const int grp = qsub * 2 + pair;
#pragma unroll 1
    for (int ph = 3; ph >= 1; --ph) {
        if (g == ph) {
#pragma unroll
            for (int rb = 0; rb < 2; ++rb)
#pragma unroll
                for (int ct = 0; ct < 4; ++ct)
#pragma unroll
                    for (int r = 0; r < 4; ++r) {
                        const int slot = (grp * 32 + rb * 16 + ct * 4 + r) * 64 + lane;
                        float v = accO[rb][ct][r] * inv[rb];
                        if (ph == 3) xbuf[slot] = v;
                        else xbuf[slot] += v;
                    }
        }
        __syncthreads();
    }
    if (g == 0) {
        float* ob = out + (size_t)b * plane;
#pragma unroll
        for (int rb = 0; rb < 2; ++rb)
#pragma unroll
            for (int ct = 0; ct < 4; ++ct)
#pragma unroll
                for (int r = 0; r < 4; ++r) {
                    float v = accO[rb][ct][r] * inv[rb] +
                              xbuf[(grp * 32 + rb * 16 + ct * 4 + r) * 64 + lane];
                    // out[c = ct*16+quad*4+r][t = q0+rb*16+l16]: coalesced over l16
                    ob[(size_t)(ct * 16 + quad * 4 + r) * TT + q0 + rb * 16 + l16] = v;
                }
    }
}

extern "C" void kernel_launch(void* const* d_in, const int* in_sizes, int n_in,
                              void* d_out, int out_size, void* d_ws, size_t ws_size,
                              hipStream_t stream) {
    const float* x1 = (const float*)d_in[0];
    const float* x2 = (const float*)d_in[1];
    ushort* kt = (ushort*)d_ws;                              // 8 MB frag-packed K/Q
    ushort* vt = (ushort*)d_ws + (size_t)2 * NB * TT * CC;   // 8 MB frag-packed V

    hipLaunchKernelGGL(prep_k, dim3(TT / 64, NB, 2), dim3(256), 0, stream, x1, x2, kt, vt);
    hipLaunchKernelGGL(attn_fused_k, dim3(32 * NB), dim3(1024), 0, stream,
                       kt, vt, (float*)d_out);
}